// Round 20
// baseline (182.640 us; speedup 1.0000x reference)
//
#include <hip/hip_runtime.h>
#include <stdint.h>

#define DIM 256
#define HID 256
#define NSEQ 512
#define NB 2
#define EPS 1e-5f

typedef __attribute__((ext_vector_type(4))) float f32x4;
typedef __attribute__((ext_vector_type(4))) short bf16x4;
typedef __attribute__((ext_vector_type(8))) short bf16x8;

// Blocks per batch: 512 diagonal (i, jt=i>>6) + 28 pairs * 64 rows = 2304
#define DIAG_BLOCKS 512
#define BATCH_BLOCKS 2304
#define NTILES (NB * BATCH_BLOCKS)      // 4608
#define PBLOCKS 512                     // persistent blocks
#define TILES_PER_BLOCK (NTILES / PBLOCKS)  // 9

__device__ __forceinline__ unsigned short f2bf(float f) {
    unsigned int u = __float_as_uint(f);
    u += 0x7fffu + ((u >> 16) & 1u);
    return (unsigned short)(u >> 16);
}

__device__ __forceinline__ float bfval(float f) {
    return __uint_as_float((unsigned)f2bf(f) << 16);
}

// gelu via Abramowitz-Stegun 7.1.26 erf (|abs err| <= 1.5e-7), branchless,
// HW rcp + exp2. R8-R19-proven at the bf16 absmax floor (0.015625).
__device__ __forceinline__ float gelu_fast(float x) {
    const float z  = x * 0.7071067811865476f;
    const float az = fabsf(z);
    const float t  = __builtin_amdgcn_rcpf(fmaf(0.3275911f, az, 1.0f));
    float p = fmaf(1.061405429f, t, -1.453152027f);
    p = fmaf(p, t,  1.421413741f);
    p = fmaf(p, t, -0.284496736f);
    p = fmaf(p, t,  0.254829592f);
    p = p * t;
    const float e = __builtin_amdgcn_exp2f(az * az * -1.4426950408889634f);
    float erfv = fmaf(-p, e, 1.0f);
    erfv = copysignf(erfv, z);
    return 0.5f * x * (1.0f + erfv);
}

// Paired-k position: element k -> 32*(k>>5) + 8*((k>>2)&3) + 4*((k>>4)&1) + (k&3).
__device__ __forceinline__ int pairpos(int k) {
    return ((k >> 5) << 5) + (((k >> 2) & 3) << 3) + (((k >> 4) & 1) << 2) + (k & 3);
}

// Fused prep: mask-layout probe + LayerNorm(x)@Wl+bl+mask -> lm; resolved mask
// -> maskr; blocks with row < HID also emit woTp; block 0 computes the
// dead-row constant cst[h] = bo[h] + sum_k bf16(lno_b[k]) * bf16(Wo[k][h]).
__global__ __launch_bounds__(256) void prep_kernel(
    const float* __restrict__ x, const void* __restrict__ mask,
    const float* __restrict__ ln_g, const float* __restrict__ ln_b,
    const float* __restrict__ Wl, const float* __restrict__ bl,
    const float* __restrict__ Wo, const float* __restrict__ lno_b,
    const float* __restrict__ bo,
    float* __restrict__ lm, unsigned short* __restrict__ woTp,
    int* __restrict__ maskr, float* __restrict__ cst)
{
    const int row = blockIdx.x;          // b*NSEQ + n
    const int t = threadIdx.x;
    const int lane = t & 63, w = t >> 6;
    __shared__ float xs[DIM];
    __shared__ float red[8];
    __shared__ int bad_s[4];

    // mask layout probe: first 1024 bytes (safe under both layouts).
    {
        const int v = ((const int*)mask)[t];
        unsigned long long bm = __ballot((v & ~1) != 0);
        if (lane == 0) bad_s[w] = (bm != 0ull) ? 1 : 0;
    }

    float v = x[row * DIM + t];
    float s = v, ss = v * v;
    #pragma unroll
    for (int o = 32; o; o >>= 1) { s += __shfl_xor(s, o); ss += __shfl_xor(ss, o); }
    if (lane == 0) { red[w] = s; red[4 + w] = ss; }
    __syncthreads();
    s  = red[0] + red[1] + red[2] + red[3];
    ss = red[4] + red[5] + red[6] + red[7];
    const float mu  = s * (1.0f / DIM);
    const float var = ss * (1.0f / DIM) - mu * mu;
    const float rs  = rsqrtf(var + EPS);
    xs[t] = (v - mu) * rs * ln_g[t] + ln_b[t];
    __syncthreads();

    float acc = bl[t];
    #pragma unroll 4
    for (int k = 0; k < DIM; k += 4) {
        float4 xv = *(const float4*)&xs[k];
        acc = fmaf(xv.x, Wl[(k + 0) * HID + t], acc);
        acc = fmaf(xv.y, Wl[(k + 1) * HID + t], acc);
        acc = fmaf(xv.z, Wl[(k + 2) * HID + t], acc);
        acc = fmaf(xv.w, Wl[(k + 3) * HID + t], acc);
    }
    const int packed = bad_s[0] | bad_s[1] | bad_s[2] | bad_s[3];
    const int mv = packed ? (int)((const unsigned char*)mask)[row]
                          : ((const int*)mask)[row];
    lm[row * HID + t] = mv ? acc : 0.0f;
    if (t == 0) maskr[row] = mv;

    if (row < HID) {                      // transpose duty for first 256 blocks
        woTp[row * HID + pairpos(t)] = f2bf(Wo[t * HID + row]);
    }
    if (row == 0) {                       // dead-row constant (bf16-rounded inputs)
        float c = bo[t];
        for (int k = 0; k < HID; ++k)
            c = fmaf(bfval(lno_b[k]), bfval(Wo[k * HID + t]), c);
        cst[t] = c;
    }
}

struct Tile { int b, i, j0, mirror, live; size_t base; };

__device__ __forceinline__ Tile decode_tile(int idx, const int* __restrict__ maskr) {
    Tile tl;
    int blk = idx;
    tl.b = 0;
    if (blk >= BATCH_BLOCKS) { tl.b = 1; blk -= BATCH_BLOCKS; }
    if (blk < DIAG_BLOCKS) {
        tl.i = blk; tl.j0 = (tl.i >> 6) * 64; tl.mirror = 0;
    } else {
        const int r2 = blk - DIAG_BLOCKS;      // 0..1791
        const int p  = r2 >> 6;                // 0..27 pair index (bi,bj), bj>bi
        const int il = r2 & 63;
        int bi = 0, start = 0;
        #pragma unroll
        for (int bb = 0; bb < 7; ++bb) {
            const int s = bb * 7 - (bb * (bb - 1)) / 2;   // 0,7,13,18,22,25,27
            if (p >= s) { bi = bb; start = s; }
        }
        const int bj = bi + 1 + (p - start);
        tl.i = bi * 64 + il;
        tl.j0 = bj * 64;
        tl.mirror = 1;
    }
    tl.base = (size_t)(tl.b * NSEQ + tl.i) * NSEQ * HID;
    tl.live = maskr[tl.b * NSEQ + tl.i] != 0;
    return tl;
}

// Persistent-block pipelined kernel: 512 threads / 8 waves, 512 blocks,
// 9 tiles each. Double-buffered LDS; per iteration {B(t) || A(t+1)} then one
// barrier -> stores issue in EVERY iteration (write pipe never phase-starved).
// Wave w owns cols [32w, 32w+32) for its WHOLE lifetime -> the 16 woTp b8
// fragments are loaded ONCE per block (9x fewer woTp reads than R17).
// A/B math and per-element MFMA order bitwise identical to R17/R19.
__global__ __launch_bounds__(512, 4) void outer_kernel(
    const float* __restrict__ lm, const unsigned short* __restrict__ woTp,
    const float* __restrict__ lno_g, const float* __restrict__ lno_b,
    const float* __restrict__ bo, const int* __restrict__ maskr,
    const float* __restrict__ cst, float* __restrict__ out)
{
    const int t    = threadIdx.x;
    const int lane = t & 63;
    const int w    = t >> 6;              // 0..7
    const int n0   = w * 32;
    const int l15  = lane & 15;
    const int q    = lane >> 4;           // 0..3

    __shared__ __align__(16) unsigned char ybuf[2][64 * 512];  // 2 x 32 KB

    // ---- wave-lifetime constants
    const float4 g4  = *(const float4*)&lno_g[lane * 4];
    const float4 bb4 = *(const float4*)&lno_b[lane * 4];
    const f32x4  cvec = *(const f32x4*)&cst[lane * 4];
    const uint2 ucst = make_uint2(
        ((unsigned)f2bf(bb4.y) << 16) | (unsigned)f2bf(bb4.x),
        ((unsigned)f2bf(bb4.w) << 16) | (unsigned)f2bf(bb4.z));
    const int wrb = ((lane >> 3) << 6) + ((lane & 3) << 4) + (((lane >> 2) & 1) << 3);
    float4 bo4[2];
    bo4[0] = *(const float4*)&bo[n0 + q * 4];
    bo4[1] = *(const float4*)&bo[n0 + 16 + q * 4];

    // b8 preload: ONCE per block lifetime (wave's columns never change).
    bf16x8 b8[16];
    #pragma unroll
    for (int kk2 = 0; kk2 < 8; ++kk2)
        #pragma unroll
        for (int nh = 0; nh < 2; ++nh)
            b8[kk2 * 2 + nh] =
                *(const bf16x8*)&woTp[(n0 + nh * 16 + l15) * HID + kk2 * 32 + q * 8];

    // ---- Phase A for one tile into buf (identical math to R17/R19)
    auto phaseA = [&](const Tile& tl, unsigned char* buf) {
        const float4 li4 = *(const float4*)&lm[(size_t)(tl.b * NSEQ + tl.i) * HID + lane * 4];
        const int mvl = maskr[tl.b * NSEQ + tl.j0 + lane];
        const unsigned long long livemask = __ballot(mvl != 0);
        #pragma unroll 4
        for (int r = 0; r < 8; ++r) {
            const int rl = w * 8 + r;
            const int off = rl * 512 + (wrb ^ ((rl & 7) << 4));
            if (!((livemask >> rl) & 1ull)) {
                *(uint2*)&buf[off] = ucst;
                continue;
            }
            const int j = tl.j0 + rl;
            float4 lj4 = *(const float4*)&lm[(size_t)(tl.b * NSEQ + j) * HID + lane * 4];
            float4 p;
            p.x = gelu_fast(li4.x * lj4.x);
            p.y = gelu_fast(li4.y * lj4.y);
            p.z = gelu_fast(li4.z * lj4.z);
            p.w = gelu_fast(li4.w * lj4.w);
            float s  = p.x + p.y + p.z + p.w;
            float ss = p.x * p.x + p.y * p.y + p.z * p.z + p.w * p.w;
            #pragma unroll
            for (int o = 32; o; o >>= 1) { s += __shfl_xor(s, o); ss += __shfl_xor(ss, o); }
            const float mu  = s * (1.0f / HID);
            const float var = ss * (1.0f / HID) - mu * mu;
            const float rs  = rsqrtf(var + EPS);
            const float y0 = (p.x - mu) * rs * g4.x + bb4.x;
            const float y1 = (p.y - mu) * rs * g4.y + bb4.y;
            const float y2 = (p.z - mu) * rs * g4.z + bb4.z;
            const float y3 = (p.w - mu) * rs * g4.w + bb4.w;
            const unsigned int u0 = ((unsigned)f2bf(y1) << 16) | (unsigned)f2bf(y0);
            const unsigned int u1 = ((unsigned)f2bf(y3) << 16) | (unsigned)f2bf(y2);
            *(uint2*)&buf[off] = make_uint2(u0, u1);
        }
    };

    // ---- Phase B (live): mi-outer, acc[2], immediate stores (R19 body)
    auto phaseB = [&](const Tile& tl, const unsigned char* buf) {
        #pragma unroll
        for (int mi = 0; mi < 4; ++mi) {
            const int rowm  = mi * 16 + l15;
            const int rbyte = rowm * 512;
            const int swz   = (rowm & 7) << 4;

            f32x4 acc[2];
            acc[0] = (f32x4){0.f, 0.f, 0.f, 0.f};
            acc[1] = (f32x4){0.f, 0.f, 0.f, 0.f};

            #pragma unroll
            for (int kk2 = 0; kk2 < 8; ++kk2) {
                const bf16x8 a8 = *(const bf16x8*)&buf[rbyte + ((kk2 * 64 + q * 16) ^ swz)];
                const bf16x4 alo = __builtin_shufflevector(a8, a8, 0, 1, 2, 3);
                const bf16x4 ahi = __builtin_shufflevector(a8, a8, 4, 5, 6, 7);
                #pragma unroll
                for (int nh = 0; nh < 2; ++nh) {
                    const bf16x8 bf8 = b8[kk2 * 2 + nh];
                    const bf16x4 blo = __builtin_shufflevector(bf8, bf8, 0, 1, 2, 3);
                    const bf16x4 bhi = __builtin_shufflevector(bf8, bf8, 4, 5, 6, 7);
#if __has_builtin(__builtin_amdgcn_mfma_f32_16x16x16bf16_1k)
                    acc[nh] = __builtin_amdgcn_mfma_f32_16x16x16bf16_1k(
                        blo, alo, acc[nh], 0, 0, 0);
                    acc[nh] = __builtin_amdgcn_mfma_f32_16x16x16bf16_1k(
                        bhi, ahi, acc[nh], 0, 0, 0);
#else
                    asm volatile("v_mfma_f32_16x16x16_bf16 %0, %1, %2, %0"
                                 : "+v"(acc[nh]) : "v"(blo), "v"(alo));
                    asm volatile("v_mfma_f32_16x16x16_bf16 %0, %1, %2, %0"
                                 : "+v"(acc[nh]) : "v"(bhi), "v"(ahi));
#endif
                }
            }

#if !__has_builtin(__builtin_amdgcn_mfma_f32_16x16x16bf16_1k)
            asm volatile("s_nop 7");
            asm volatile("s_nop 7");
            asm volatile("" : "+v"(acc[0]), "+v"(acc[1]));
#endif

            const int j = tl.j0 + rowm;
            const size_t prow = tl.base + (size_t)j * HID;
            const size_t mrow = ((size_t)(tl.b * NSEQ + j) * NSEQ + tl.i) * HID;
            #pragma unroll
            for (int nh = 0; nh < 2; ++nh) {
                const int h0 = n0 + nh * 16 + q * 4;
                f32x4 o;
                o[0] = acc[nh][0] + bo4[nh].x;
                o[1] = acc[nh][1] + bo4[nh].y;
                o[2] = acc[nh][2] + bo4[nh].z;
                o[3] = acc[nh][3] + bo4[nh].w;
                *(f32x4*)&out[prow + h0] = o;
                if (tl.mirror)
                    *(f32x4*)&out[mrow + h0] = o;
            }
        }
    };

    // ---- Phase B (dead): constant-row broadcast
    auto deadB = [&](const Tile& tl) {
        #pragma unroll
        for (int r = 0; r < 8; ++r) {
            const int j = tl.j0 + w * 8 + r;
            *(f32x4*)&out[tl.base + (size_t)j * HID + lane * 4] = cvec;
            if (tl.mirror)
                *(f32x4*)&out[((size_t)(tl.b * NSEQ + j) * NSEQ + tl.i) * HID + lane * 4] = cvec;
        }
    };

    // ---- pipeline over 9 tiles
    const int tile0 = (int)blockIdx.x * TILES_PER_BLOCK;

    Tile cur = decode_tile(tile0, maskr);
    if (cur.live) phaseA(cur, ybuf[0]);
    __syncthreads();

    for (int tt = 0; tt < TILES_PER_BLOCK; ++tt) {
        // B(t): stores issue every iteration (live MFMA path or dead broadcast)
        if (cur.live) phaseB(cur, ybuf[tt & 1]);
        else          deadB(cur);

        // A(t+1) into the other buffer — independent of B(t)
        Tile nxt;
        if (tt + 1 < TILES_PER_BLOCK) {
            nxt = decode_tile(tile0 + tt + 1, maskr);
            if (nxt.live) phaseA(nxt, ybuf[(tt + 1) & 1]);
        }
        __syncthreads();
        cur = nxt;
    }
}

extern "C" void kernel_launch(void* const* d_in, const int* in_sizes, int n_in,
                              void* d_out, int out_size, void* d_ws, size_t ws_size,
                              hipStream_t stream) {
    (void)in_sizes; (void)n_in; (void)out_size; (void)ws_size;
    const float* x     = (const float*)d_in[0];
    const void*  mask  = d_in[1];
    const float* ln_g  = (const float*)d_in[2];
    const float* ln_b  = (const float*)d_in[3];
    const float* Wl    = (const float*)d_in[4];
    const float* bl    = (const float*)d_in[5];
    const float* Wo    = (const float*)d_in[6];
    const float* bo    = (const float*)d_in[7];
    const float* lno_g = (const float*)d_in[8];
    const float* lno_b = (const float*)d_in[9];

    char* ws = (char*)d_ws;
    float*          lm    = (float*)ws;                              // 1 MB
    unsigned short* woTp  = (unsigned short*)(ws + (size_t)NB * NSEQ * HID * 4);  // 128 KB
    int*            maskr = (int*)(ws + (size_t)NB * NSEQ * HID * 4 + HID * HID * 2);
    float*          cst   = (float*)(ws + (size_t)NB * NSEQ * HID * 4 + HID * HID * 2
                                        + NB * NSEQ * 4);

    prep_kernel<<<NB * NSEQ, 256, 0, stream>>>(x, mask, ln_g, ln_b, Wl, bl, Wo,
                                               lno_b, bo, lm, woTp, maskr, cst);
    outer_kernel<<<PBLOCKS, 512, 0, stream>>>(
        lm, woTp, lno_g, lno_b, bo, maskr, cst, (float*)d_out);
}

// Round 21
// 150.359 us; speedup vs baseline: 1.2147x; 1.2147x over previous
//
#include <hip/hip_runtime.h>
#include <stdint.h>

#define DIM 256
#define HID 256
#define NSEQ 512
#define NB 2
#define EPS 1e-5f

typedef __attribute__((ext_vector_type(4))) float f32x4;
typedef __attribute__((ext_vector_type(4))) short bf16x4;
typedef __attribute__((ext_vector_type(8))) short bf16x8;

// Blocks per batch: 512 diagonal (i, jt=i>>6) + 28 pairs * 64 rows = 2304
#define DIAG_BLOCKS 512
#define BATCH_BLOCKS 2304

__device__ __forceinline__ unsigned short f2bf(float f) {
    unsigned int u = __float_as_uint(f);
    u += 0x7fffu + ((u >> 16) & 1u);
    return (unsigned short)(u >> 16);
}

__device__ __forceinline__ float bfval(float f) {
    return __uint_as_float((unsigned)f2bf(f) << 16);
}

// gelu via Abramowitz-Stegun 7.1.26 erf (|abs err| <= 1.5e-7), branchless,
// HW rcp + exp2. R8-R20-proven at the bf16 absmax floor (0.015625).
__device__ __forceinline__ float gelu_fast(float x) {
    const float z  = x * 0.7071067811865476f;
    const float az = fabsf(z);
    const float t  = __builtin_amdgcn_rcpf(fmaf(0.3275911f, az, 1.0f));
    float p = fmaf(1.061405429f, t, -1.453152027f);
    p = fmaf(p, t,  1.421413741f);
    p = fmaf(p, t, -0.284496736f);
    p = fmaf(p, t,  0.254829592f);
    p = p * t;
    const float e = __builtin_amdgcn_exp2f(az * az * -1.4426950408889634f);
    float erfv = fmaf(-p, e, 1.0f);
    erfv = copysignf(erfv, z);
    return 0.5f * x * (1.0f + erfv);
}

// Paired-k position: element k -> 32*(k>>5) + 8*((k>>2)&3) + 4*((k>>4)&1) + (k&3).
__device__ __forceinline__ int pairpos(int k) {
    return ((k >> 5) << 5) + (((k >> 2) & 3) << 3) + (((k >> 4) & 1) << 2) + (k & 3);
}

// Fused prep: mask-layout probe + LayerNorm(x)@Wl+bl+mask -> lm; resolved mask
// -> maskr; blocks with row < HID also emit woTp; block 0 computes the
// dead-row constant cst[h] = bo[h] + sum_k bf16(lno_b[k]) * bf16(Wo[k][h]).
__global__ __launch_bounds__(256) void prep_kernel(
    const float* __restrict__ x, const void* __restrict__ mask,
    const float* __restrict__ ln_g, const float* __restrict__ ln_b,
    const float* __restrict__ Wl, const float* __restrict__ bl,
    const float* __restrict__ Wo, const float* __restrict__ lno_b,
    const float* __restrict__ bo,
    float* __restrict__ lm, unsigned short* __restrict__ woTp,
    int* __restrict__ maskr, float* __restrict__ cst)
{
    const int row = blockIdx.x;          // b*NSEQ + n
    const int t = threadIdx.x;
    const int lane = t & 63, w = t >> 6;
    __shared__ float xs[DIM];
    __shared__ float red[8];
    __shared__ int bad_s[4];

    // mask layout probe: first 1024 bytes (safe under both layouts).
    {
        const int v = ((const int*)mask)[t];
        unsigned long long bm = __ballot((v & ~1) != 0);
        if (lane == 0) bad_s[w] = (bm != 0ull) ? 1 : 0;
    }

    float v = x[row * DIM + t];
    float s = v, ss = v * v;
    #pragma unroll
    for (int o = 32; o; o >>= 1) { s += __shfl_xor(s, o); ss += __shfl_xor(ss, o); }
    if (lane == 0) { red[w] = s; red[4 + w] = ss; }
    __syncthreads();
    s  = red[0] + red[1] + red[2] + red[3];
    ss = red[4] + red[5] + red[6] + red[7];
    const float mu  = s * (1.0f / DIM);
    const float var = ss * (1.0f / DIM) - mu * mu;
    const float rs  = rsqrtf(var + EPS);
    xs[t] = (v - mu) * rs * ln_g[t] + ln_b[t];
    __syncthreads();

    float acc = bl[t];
    #pragma unroll 4
    for (int k = 0; k < DIM; k += 4) {
        float4 xv = *(const float4*)&xs[k];
        acc = fmaf(xv.x, Wl[(k + 0) * HID + t], acc);
        acc = fmaf(xv.y, Wl[(k + 1) * HID + t], acc);
        acc = fmaf(xv.z, Wl[(k + 2) * HID + t], acc);
        acc = fmaf(xv.w, Wl[(k + 3) * HID + t], acc);
    }
    const int packed = bad_s[0] | bad_s[1] | bad_s[2] | bad_s[3];
    const int mv = packed ? (int)((const unsigned char*)mask)[row]
                          : ((const int*)mask)[row];
    lm[row * HID + t] = mv ? acc : 0.0f;
    if (t == 0) maskr[row] = mv;

    if (row < HID) {                      // transpose duty for first 256 blocks
        woTp[row * HID + pairpos(t)] = f2bf(Wo[t * HID + row]);
    }
    if (row == 0) {                       // dead-row constant (bf16-rounded inputs)
        float c = bo[t];
        for (int k = 0; k < HID; ++k)
            c = fmaf(bfval(lno_b[k]), bfval(Wo[k * HID + t]), c);
        cst[t] = c;
    }
}

// Main fused kernel: 512 threads / 8 waves (R17 structure, best = 149.5 us).
// Symmetry (R7-verified): upper triangle only; off-diagonal mirror-write.
// Phase A: wave w computes rows [8w, 8w+8), with ALL 8 lj4 row-loads
// prefetched into registers before the compute loop (hides L2 latency once
// instead of 8x serially — the only lever that has ever moved this kernel).
// Phase B: wave w owns ALL 64 j-rows x 32 h-cols via acc[4][2]; b8 traffic
// maximal-reuse. Per-block live mask via one ballot. Math bitwise = R17.
__global__ __launch_bounds__(512) void outer_kernel(
    const float* __restrict__ lm, const unsigned short* __restrict__ woTp,
    const float* __restrict__ lno_g, const float* __restrict__ lno_b,
    const float* __restrict__ bo, const int* __restrict__ maskr,
    const float* __restrict__ cst, float* __restrict__ out)
{
    // ---- block decode: (b, i, jt, mirror) ----
    int blk = (int)blockIdx.x;
    int b = 0;
    if (blk >= BATCH_BLOCKS) { b = 1; blk -= BATCH_BLOCKS; }
    int i, jt, mirror;
    if (blk < DIAG_BLOCKS) {
        i = blk; jt = i >> 6; mirror = 0;
    } else {
        const int r2 = blk - DIAG_BLOCKS;      // 0..1791
        const int p  = r2 >> 6;                // 0..27 pair index (bi,bj), bj>bi
        const int il = r2 & 63;
        int bi = 0, start = 0;
        #pragma unroll
        for (int bb = 0; bb < 7; ++bb) {
            const int s = bb * 7 - (bb * (bb - 1)) / 2;   // 0,7,13,18,22,25,27
            if (p >= s) { bi = bb; start = s; }
        }
        const int bj = bi + 1 + (p - start);
        i = bi * 64 + il;
        jt = bj;
        mirror = 1;
    }
    const int j0  = jt * 64;
    const int t    = threadIdx.x;
    const int lane = t & 63;
    const int w    = t >> 6;              // 0..7
    const size_t base = (size_t)(b * NSEQ + i) * NSEQ * HID;

    // ---- dead-i fast path: all 64 rows (and mirrors) are the constant row
    if (maskr[b * NSEQ + i] == 0) {
        const f32x4 c = *(const f32x4*)&cst[lane * 4];
        #pragma unroll
        for (int r = 0; r < 8; ++r) {
            const int j = j0 + w * 8 + r;
            *(f32x4*)&out[base + (size_t)j * HID + lane * 4] = c;
            if (mirror)
                *(f32x4*)&out[((size_t)(b * NSEQ + j) * NSEQ + i) * HID + lane * 4] = c;
        }
        return;
    }

    __shared__ __align__(16) unsigned char ybuf[64 * 512];  // 64 rows x 256 bf16 (paired-k)

    const float4 li4 = *(const float4*)&lm[(size_t)(b * NSEQ + i) * HID + lane * 4];
    const float4 g4  = *(const float4*)&lno_g[lane * 4];
    const float4 bb4 = *(const float4*)&lno_b[lane * 4];

    // Per-block live-row bitmask: one coalesced load + ballot, no per-row loads.
    const int mvl = maskr[b * NSEQ + j0 + lane];
    const unsigned long long livemask = __ballot(mvl != 0);

    // Paired-k write slot for this lane's k = 4*lane .. 4*lane+3 (8 bytes):
    const int wrb = ((lane >> 3) << 6) + ((lane & 3) << 4) + (((lane >> 2) & 1) << 3);

    // Dead-row Y fragment: y = lno_b exactly (bitwise = full computation)
    const uint2 ucst = make_uint2(
        ((unsigned)f2bf(bb4.y) << 16) | (unsigned)f2bf(bb4.x),
        ((unsigned)f2bf(bb4.w) << 16) | (unsigned)f2bf(bb4.z));

    // ---------------- Phase A: wave w handles local rows [8w, 8w+8)
    // Prefetch all 8 lj4 row-fragments first: loads issue back-to-back,
    // L2 latency overlaps across them instead of serializing per row.
    float4 lj4s[8];
    #pragma unroll
    for (int r = 0; r < 8; ++r) {
        const int j = j0 + w * 8 + r;
        lj4s[r] = *(const float4*)&lm[(size_t)(b * NSEQ + j) * HID + lane * 4];
    }

    #pragma unroll
    for (int r = 0; r < 8; ++r) {
        const int rl = w * 8 + r;
        const int off = rl * 512 + (wrb ^ ((rl & 7) << 4));
        if (!((livemask >> rl) & 1ull)) {
            *(uint2*)&ybuf[off] = ucst;
            continue;
        }
        const float4 lj4 = lj4s[r];
        float4 p;
        p.x = gelu_fast(li4.x * lj4.x);
        p.y = gelu_fast(li4.y * lj4.y);
        p.z = gelu_fast(li4.z * lj4.z);
        p.w = gelu_fast(li4.w * lj4.w);
        float s  = p.x + p.y + p.z + p.w;
        float ss = p.x * p.x + p.y * p.y + p.z * p.z + p.w * p.w;
        #pragma unroll
        for (int o = 32; o; o >>= 1) { s += __shfl_xor(s, o); ss += __shfl_xor(ss, o); }
        const float mu  = s * (1.0f / HID);
        const float var = ss * (1.0f / HID) - mu * mu;
        const float rs  = rsqrtf(var + EPS);
        const float y0 = (p.x - mu) * rs * g4.x + bb4.x;
        const float y1 = (p.y - mu) * rs * g4.y + bb4.y;
        const float y2 = (p.z - mu) * rs * g4.z + bb4.z;
        const float y3 = (p.w - mu) * rs * g4.w + bb4.w;
        const unsigned int u0 = ((unsigned)f2bf(y1) << 16) | (unsigned)f2bf(y0);
        const unsigned int u1 = ((unsigned)f2bf(y3) << 16) | (unsigned)f2bf(y2);
        *(uint2*)&ybuf[off] = make_uint2(u0, u1);
    }
    __syncthreads();

    // ---------------- Phase B: wave w owns cols [32w, 32w+32), all 64 j rows
    const int n0  = w * 32;
    const int l15 = lane & 15;
    const int q   = lane >> 4;           // 0..3

    f32x4 acc[4][2];
    #pragma unroll
    for (int mi = 0; mi < 4; ++mi)
        #pragma unroll
        for (int nh = 0; nh < 2; ++nh)
            acc[mi][nh] = (f32x4){0.f, 0.f, 0.f, 0.f};

#if !__has_builtin(__builtin_amdgcn_mfma_f32_16x16x16bf16_1k)
    #pragma unroll
    for (int mi = 0; mi < 4; ++mi)
        #pragma unroll
        for (int nh = 0; nh < 2; ++nh)
            asm volatile("" : "+v"(acc[mi][nh]));
    asm volatile("s_nop 1");
#endif

    #pragma unroll
    for (int kk2 = 0; kk2 < 8; ++kk2) {        // K = 256, 2 k-steps per iter
        const int pb = kk2 * 64 + q * 16;      // paired-k byte offset within row
        bf16x8 a8[4], b8[2];
        #pragma unroll
        for (int mi = 0; mi < 4; ++mi) {
            const int rowm = mi * 16 + l15;
            a8[mi] = *(const bf16x8*)&ybuf[rowm * 512 + (pb ^ ((rowm & 7) << 4))];
        }
        #pragma unroll
        for (int nh = 0; nh < 2; ++nh) {
            const int col = n0 + nh * 16 + l15;
            b8[nh] = *(const bf16x8*)&woTp[col * HID + kk2 * 32 + q * 8];
        }
        #pragma unroll
        for (int mi = 0; mi < 4; ++mi) {
            const bf16x4 alo = __builtin_shufflevector(a8[mi], a8[mi], 0, 1, 2, 3);
            const bf16x4 ahi = __builtin_shufflevector(a8[mi], a8[mi], 4, 5, 6, 7);
            #pragma unroll
            for (int nh = 0; nh < 2; ++nh) {
                const bf16x4 blo = __builtin_shufflevector(b8[nh], b8[nh], 0, 1, 2, 3);
                const bf16x4 bhi = __builtin_shufflevector(b8[nh], b8[nh], 4, 5, 6, 7);
#if __has_builtin(__builtin_amdgcn_mfma_f32_16x16x16bf16_1k)
                acc[mi][nh] = __builtin_amdgcn_mfma_f32_16x16x16bf16_1k(
                    blo, alo, acc[mi][nh], 0, 0, 0);
                acc[mi][nh] = __builtin_amdgcn_mfma_f32_16x16x16bf16_1k(
                    bhi, ahi, acc[mi][nh], 0, 0, 0);
#else
                asm volatile("v_mfma_f32_16x16x16_bf16 %0, %1, %2, %0"
                             : "+v"(acc[mi][nh]) : "v"(blo), "v"(alo));
                asm volatile("v_mfma_f32_16x16x16_bf16 %0, %1, %2, %0"
                             : "+v"(acc[mi][nh]) : "v"(bhi), "v"(ahi));
#endif
            }
        }
    }

#if !__has_builtin(__builtin_amdgcn_mfma_f32_16x16x16bf16_1k)
    asm volatile("s_nop 7");
    asm volatile("s_nop 7");
    #pragma unroll
    for (int mi = 0; mi < 4; ++mi)
        #pragma unroll
        for (int nh = 0; nh < 2; ++nh)
            asm volatile("" : "+v"(acc[mi][nh]));
#endif

    // Stores: lane l, reg r -> j = j0 + mi*16 + (l&15), h = n0 + nh*16 + 4q + r.
    // Plain L2-cached f32x4 stores, primary + mirror.
    #pragma unroll
    for (int mi = 0; mi < 4; ++mi) {
        const int j = j0 + mi * 16 + l15;
        const size_t prow = base + (size_t)j * HID;
        const size_t mrow = ((size_t)(b * NSEQ + j) * NSEQ + i) * HID;
        #pragma unroll
        for (int nh = 0; nh < 2; ++nh) {
            const int h0 = n0 + nh * 16 + q * 4;
            const float4 bo4 = *(const float4*)&bo[h0];
            f32x4 o;
            o[0] = acc[mi][nh][0] + bo4.x;
            o[1] = acc[mi][nh][1] + bo4.y;
            o[2] = acc[mi][nh][2] + bo4.z;
            o[3] = acc[mi][nh][3] + bo4.w;
            *(f32x4*)&out[prow + h0] = o;
            if (mirror)
                *(f32x4*)&out[mrow + h0] = o;
        }
    }
}

extern "C" void kernel_launch(void* const* d_in, const int* in_sizes, int n_in,
                              void* d_out, int out_size, void* d_ws, size_t ws_size,
                              hipStream_t stream) {
    (void)in_sizes; (void)n_in; (void)out_size; (void)ws_size;
    const float* x     = (const float*)d_in[0];
    const void*  mask  = d_in[1];
    const float* ln_g  = (const float*)d_in[2];
    const float* ln_b  = (const float*)d_in[3];
    const float* Wl    = (const float*)d_in[4];
    const float* bl    = (const float*)d_in[5];
    const float* Wo    = (const float*)d_in[6];
    const float* bo    = (const float*)d_in[7];
    const float* lno_g = (const float*)d_in[8];
    const float* lno_b = (const float*)d_in[9];

    char* ws = (char*)d_ws;
    float*          lm    = (float*)ws;                              // 1 MB
    unsigned short* woTp  = (unsigned short*)(ws + (size_t)NB * NSEQ * HID * 4);  // 128 KB
    int*            maskr = (int*)(ws + (size_t)NB * NSEQ * HID * 4 + HID * HID * 2);
    float*          cst   = (float*)(ws + (size_t)NB * NSEQ * HID * 4 + HID * HID * 2
                                        + NB * NSEQ * 4);

    prep_kernel<<<NB * NSEQ, 256, 0, stream>>>(x, mask, ln_g, ln_b, Wl, bl, Wo,
                                               lno_b, bo, lm, woTp, maskr, cst);
    outer_kernel<<<NB * BATCH_BLOCKS, 512, 0, stream>>>(
        lm, woTp, lno_g, lno_b, bo, maskr, cst, (float*)d_out);
}

// Round 22
// 144.303 us; speedup vs baseline: 1.2657x; 1.0420x over previous
//
#include <hip/hip_runtime.h>
#include <stdint.h>

#define DIM 256
#define HID 256
#define NSEQ 512
#define NB 2
#define EPS 1e-5f

typedef __attribute__((ext_vector_type(4))) float f32x4;
typedef __attribute__((ext_vector_type(4))) short bf16x4;
typedef __attribute__((ext_vector_type(8))) short bf16x8;

// Blocks per batch: 512 diagonal (i, jt=i>>6) + 28 pairs * 64 rows = 2304
#define DIAG_BLOCKS 512
#define BATCH_BLOCKS 2304

__device__ __forceinline__ unsigned short f2bf(float f) {
    unsigned int u = __float_as_uint(f);
    u += 0x7fffu + ((u >> 16) & 1u);
    return (unsigned short)(u >> 16);
}

__device__ __forceinline__ float bfval(float f) {
    return __uint_as_float((unsigned)f2bf(f) << 16);
}

// gelu via Abramowitz-Stegun 7.1.26 erf (|abs err| <= 1.5e-7), branchless,
// HW rcp + exp2. R8-R21-proven at the bf16 absmax floor (0.015625).
__device__ __forceinline__ float gelu_fast(float x) {
    const float z  = x * 0.7071067811865476f;
    const float az = fabsf(z);
    const float t  = __builtin_amdgcn_rcpf(fmaf(0.3275911f, az, 1.0f));
    float p = fmaf(1.061405429f, t, -1.453152027f);
    p = fmaf(p, t,  1.421413741f);
    p = fmaf(p, t, -0.284496736f);
    p = fmaf(p, t,  0.254829592f);
    p = p * t;
    const float e = __builtin_amdgcn_exp2f(az * az * -1.4426950408889634f);
    float erfv = fmaf(-p, e, 1.0f);
    erfv = copysignf(erfv, z);
    return 0.5f * x * (1.0f + erfv);
}

// Paired-k position: element k -> 32*(k>>5) + 8*((k>>2)&3) + 4*((k>>4)&1) + (k&3).
__device__ __forceinline__ int pairpos(int k) {
    return ((k >> 5) << 5) + (((k >> 2) & 3) << 3) + (((k >> 4) & 1) << 2) + (k & 3);
}

// Fused prep: mask-layout probe + LayerNorm(x)@Wl+bl+mask -> lm; resolved mask
// -> maskr; blocks with row < HID also emit woTp; block 0 computes the
// dead-row constant cst[h] = bo[h] + sum_k bf16(lno_b[k]) * bf16(Wo[k][h]).
__global__ __launch_bounds__(256) void prep_kernel(
    const float* __restrict__ x, const void* __restrict__ mask,
    const float* __restrict__ ln_g, const float* __restrict__ ln_b,
    const float* __restrict__ Wl, const float* __restrict__ bl,
    const float* __restrict__ Wo, const float* __restrict__ lno_b,
    const float* __restrict__ bo,
    float* __restrict__ lm, unsigned short* __restrict__ woTp,
    int* __restrict__ maskr, float* __restrict__ cst)
{
    const int row = blockIdx.x;          // b*NSEQ + n
    const int t = threadIdx.x;
    const int lane = t & 63, w = t >> 6;
    __shared__ float xs[DIM];
    __shared__ float red[8];
    __shared__ int bad_s[4];

    // mask layout probe: first 1024 bytes (safe under both layouts).
    {
        const int v = ((const int*)mask)[t];
        unsigned long long bm = __ballot((v & ~1) != 0);
        if (lane == 0) bad_s[w] = (bm != 0ull) ? 1 : 0;
    }

    float v = x[row * DIM + t];
    float s = v, ss = v * v;
    #pragma unroll
    for (int o = 32; o; o >>= 1) { s += __shfl_xor(s, o); ss += __shfl_xor(ss, o); }
    if (lane == 0) { red[w] = s; red[4 + w] = ss; }
    __syncthreads();
    s  = red[0] + red[1] + red[2] + red[3];
    ss = red[4] + red[5] + red[6] + red[7];
    const float mu  = s * (1.0f / DIM);
    const float var = ss * (1.0f / DIM) - mu * mu;
    const float rs  = rsqrtf(var + EPS);
    xs[t] = (v - mu) * rs * ln_g[t] + ln_b[t];
    __syncthreads();

    float acc = bl[t];
    #pragma unroll 4
    for (int k = 0; k < DIM; k += 4) {
        float4 xv = *(const float4*)&xs[k];
        acc = fmaf(xv.x, Wl[(k + 0) * HID + t], acc);
        acc = fmaf(xv.y, Wl[(k + 1) * HID + t], acc);
        acc = fmaf(xv.z, Wl[(k + 2) * HID + t], acc);
        acc = fmaf(xv.w, Wl[(k + 3) * HID + t], acc);
    }
    const int packed = bad_s[0] | bad_s[1] | bad_s[2] | bad_s[3];
    const int mv = packed ? (int)((const unsigned char*)mask)[row]
                          : ((const int*)mask)[row];
    lm[row * HID + t] = mv ? acc : 0.0f;
    if (t == 0) maskr[row] = mv;

    if (row < HID) {                      // transpose duty for first 256 blocks
        woTp[row * HID + pairpos(t)] = f2bf(Wo[t * HID + row]);
    }
    if (row == 0) {                       // dead-row constant (bf16-rounded inputs)
        float c = bo[t];
        for (int k = 0; k < HID; ++k)
            c = fmaf(bfval(lno_b[k]), bfval(Wo[k * HID + t]), c);
        cst[t] = c;
    }
}

// Main fused kernel: 512 threads / 8 waves (R17 structure, best = 149.5 us).
// Symmetry (R7-verified): upper triangle only; off-diagonal mirror-write.
// NEW vs R17: dead-j rows of LIVE blocks store their (constant) output row
// DURING Phase A — ~25% of all output bytes now issue in the previously
// store-silent phase; Phase B skips those rows (per-lane livemask predicate).
// Total bytes identical; every location written exactly once. Live-row math
// and stores bitwise identical to R17.
__global__ __launch_bounds__(512) void outer_kernel(
    const float* __restrict__ lm, const unsigned short* __restrict__ woTp,
    const float* __restrict__ lno_g, const float* __restrict__ lno_b,
    const float* __restrict__ bo, const int* __restrict__ maskr,
    const float* __restrict__ cst, float* __restrict__ out)
{
    // ---- block decode: (b, i, jt, mirror) ----
    int blk = (int)blockIdx.x;
    int b = 0;
    if (blk >= BATCH_BLOCKS) { b = 1; blk -= BATCH_BLOCKS; }
    int i, jt, mirror;
    if (blk < DIAG_BLOCKS) {
        i = blk; jt = i >> 6; mirror = 0;
    } else {
        const int r2 = blk - DIAG_BLOCKS;      // 0..1791
        const int p  = r2 >> 6;                // 0..27 pair index (bi,bj), bj>bi
        const int il = r2 & 63;
        int bi = 0, start = 0;
        #pragma unroll
        for (int bb = 0; bb < 7; ++bb) {
            const int s = bb * 7 - (bb * (bb - 1)) / 2;   // 0,7,13,18,22,25,27
            if (p >= s) { bi = bb; start = s; }
        }
        const int bj = bi + 1 + (p - start);
        i = bi * 64 + il;
        jt = bj;
        mirror = 1;
    }
    const int j0  = jt * 64;
    const int t    = threadIdx.x;
    const int lane = t & 63;
    const int w    = t >> 6;              // 0..7
    const size_t base = (size_t)(b * NSEQ + i) * NSEQ * HID;

    const f32x4 cvec = *(const f32x4*)&cst[lane * 4];

    // ---- dead-i fast path: all 64 rows (and mirrors) are the constant row
    if (maskr[b * NSEQ + i] == 0) {
        #pragma unroll
        for (int r = 0; r < 8; ++r) {
            const int j = j0 + w * 8 + r;
            *(f32x4*)&out[base + (size_t)j * HID + lane * 4] = cvec;
            if (mirror)
                *(f32x4*)&out[((size_t)(b * NSEQ + j) * NSEQ + i) * HID + lane * 4] = cvec;
        }
        return;
    }

    __shared__ __align__(16) unsigned char ybuf[64 * 512];  // 64 rows x 256 bf16 (paired-k)

    const float4 li4 = *(const float4*)&lm[(size_t)(b * NSEQ + i) * HID + lane * 4];
    const float4 g4  = *(const float4*)&lno_g[lane * 4];
    const float4 bb4 = *(const float4*)&lno_b[lane * 4];

    // Per-block live-row bitmask: one coalesced load + ballot, no per-row loads.
    const int mvl = maskr[b * NSEQ + j0 + lane];
    const unsigned long long livemask = __ballot(mvl != 0);

    // Paired-k write slot for this lane's k = 4*lane .. 4*lane+3 (8 bytes):
    const int wrb = ((lane >> 3) << 6) + ((lane & 3) << 4) + (((lane >> 2) & 1) << 3);

    // Dead-row Y fragment: y = lno_b exactly (bitwise = full computation)
    const uint2 ucst = make_uint2(
        ((unsigned)f2bf(bb4.y) << 16) | (unsigned)f2bf(bb4.x),
        ((unsigned)f2bf(bb4.w) << 16) | (unsigned)f2bf(bb4.z));

    // ---------------- Phase A: wave w handles local rows [8w, 8w+8).
    // Dead rows: LDS gets the lno_b fragment AND the output row (constant)
    // stores NOW — real store traffic inside the formerly store-silent phase.
    #pragma unroll 4
    for (int r = 0; r < 8; ++r) {
        const int rl = w * 8 + r;
        const int j  = j0 + rl;
        const int off = rl * 512 + (wrb ^ ((rl & 7) << 4));
        if (!((livemask >> rl) & 1ull)) {
            *(uint2*)&ybuf[off] = ucst;
            *(f32x4*)&out[base + (size_t)j * HID + lane * 4] = cvec;
            if (mirror)
                *(f32x4*)&out[((size_t)(b * NSEQ + j) * NSEQ + i) * HID + lane * 4] = cvec;
            continue;
        }
        float4 lj4 = *(const float4*)&lm[(size_t)(b * NSEQ + j) * HID + lane * 4];
        float4 p;
        p.x = gelu_fast(li4.x * lj4.x);
        p.y = gelu_fast(li4.y * lj4.y);
        p.z = gelu_fast(li4.z * lj4.z);
        p.w = gelu_fast(li4.w * lj4.w);
        float s  = p.x + p.y + p.z + p.w;
        float ss = p.x * p.x + p.y * p.y + p.z * p.z + p.w * p.w;
        #pragma unroll
        for (int o = 32; o; o >>= 1) { s += __shfl_xor(s, o); ss += __shfl_xor(ss, o); }
        const float mu  = s * (1.0f / HID);
        const float var = ss * (1.0f / HID) - mu * mu;
        const float rs  = rsqrtf(var + EPS);
        const float y0 = (p.x - mu) * rs * g4.x + bb4.x;
        const float y1 = (p.y - mu) * rs * g4.y + bb4.y;
        const float y2 = (p.z - mu) * rs * g4.z + bb4.z;
        const float y3 = (p.w - mu) * rs * g4.w + bb4.w;
        const unsigned int u0 = ((unsigned)f2bf(y1) << 16) | (unsigned)f2bf(y0);
        const unsigned int u1 = ((unsigned)f2bf(y3) << 16) | (unsigned)f2bf(y2);
        *(uint2*)&ybuf[off] = make_uint2(u0, u1);
    }
    __syncthreads();

    // ---------------- Phase B: wave w owns cols [32w, 32w+32), all 64 j rows
    const int n0  = w * 32;
    const int l15 = lane & 15;
    const int q   = lane >> 4;           // 0..3

    f32x4 acc[4][2];
    #pragma unroll
    for (int mi = 0; mi < 4; ++mi)
        #pragma unroll
        for (int nh = 0; nh < 2; ++nh)
            acc[mi][nh] = (f32x4){0.f, 0.f, 0.f, 0.f};

#if !__has_builtin(__builtin_amdgcn_mfma_f32_16x16x16bf16_1k)
    #pragma unroll
    for (int mi = 0; mi < 4; ++mi)
        #pragma unroll
        for (int nh = 0; nh < 2; ++nh)
            asm volatile("" : "+v"(acc[mi][nh]));
    asm volatile("s_nop 1");
#endif

    #pragma unroll
    for (int kk2 = 0; kk2 < 8; ++kk2) {        // K = 256, 2 k-steps per iter
        const int pb = kk2 * 64 + q * 16;      // paired-k byte offset within row
        bf16x8 a8[4], b8[2];
        #pragma unroll
        for (int mi = 0; mi < 4; ++mi) {
            const int rowm = mi * 16 + l15;
            a8[mi] = *(const bf16x8*)&ybuf[rowm * 512 + (pb ^ ((rowm & 7) << 4))];
        }
        #pragma unroll
        for (int nh = 0; nh < 2; ++nh) {
            const int col = n0 + nh * 16 + l15;
            b8[nh] = *(const bf16x8*)&woTp[col * HID + kk2 * 32 + q * 8];
        }
        #pragma unroll
        for (int mi = 0; mi < 4; ++mi) {
            const bf16x4 alo = __builtin_shufflevector(a8[mi], a8[mi], 0, 1, 2, 3);
            const bf16x4 ahi = __builtin_shufflevector(a8[mi], a8[mi], 4, 5, 6, 7);
            #pragma unroll
            for (int nh = 0; nh < 2; ++nh) {
                const bf16x4 blo = __builtin_shufflevector(b8[nh], b8[nh], 0, 1, 2, 3);
                const bf16x4 bhi = __builtin_shufflevector(b8[nh], b8[nh], 4, 5, 6, 7);
#if __has_builtin(__builtin_amdgcn_mfma_f32_16x16x16bf16_1k)
                acc[mi][nh] = __builtin_amdgcn_mfma_f32_16x16x16bf16_1k(
                    blo, alo, acc[mi][nh], 0, 0, 0);
                acc[mi][nh] = __builtin_amdgcn_mfma_f32_16x16x16bf16_1k(
                    bhi, ahi, acc[mi][nh], 0, 0, 0);
#else
                asm volatile("v_mfma_f32_16x16x16_bf16 %0, %1, %2, %0"
                             : "+v"(acc[mi][nh]) : "v"(blo), "v"(alo));
                asm volatile("v_mfma_f32_16x16x16_bf16 %0, %1, %2, %0"
                             : "+v"(acc[mi][nh]) : "v"(bhi), "v"(ahi));
#endif
            }
        }
    }

#if !__has_builtin(__builtin_amdgcn_mfma_f32_16x16x16bf16_1k)
    asm volatile("s_nop 7");
    asm volatile("s_nop 7");
    #pragma unroll
    for (int mi = 0; mi < 4; ++mi)
        #pragma unroll
        for (int nh = 0; nh < 2; ++nh)
            asm volatile("" : "+v"(acc[mi][nh]));
#endif

    // Stores: lane l, reg r -> j = j0 + mi*16 + (l&15), h = n0 + nh*16 + 4q + r.
    // Dead rows were already written in Phase A -> per-lane predicate skips them.
    #pragma unroll
    for (int mi = 0; mi < 4; ++mi) {
        const int rowm = mi * 16 + l15;
        if (!((livemask >> rowm) & 1ull)) continue;   // written during Phase A
        const int j = j0 + rowm;
        const size_t prow = base + (size_t)j * HID;
        const size_t mrow = ((size_t)(b * NSEQ + j) * NSEQ + i) * HID;
        #pragma unroll
        for (int nh = 0; nh < 2; ++nh) {
            const int h0 = n0 + nh * 16 + q * 4;
            const float4 bo4 = *(const float4*)&bo[h0];
            f32x4 o;
            o[0] = acc[mi][nh][0] + bo4.x;
            o[1] = acc[mi][nh][1] + bo4.y;
            o[2] = acc[mi][nh][2] + bo4.z;
            o[3] = acc[mi][nh][3] + bo4.w;
            *(f32x4*)&out[prow + h0] = o;
            if (mirror)
                *(f32x4*)&out[mrow + h0] = o;
        }
    }
}

extern "C" void kernel_launch(void* const* d_in, const int* in_sizes, int n_in,
                              void* d_out, int out_size, void* d_ws, size_t ws_size,
                              hipStream_t stream) {
    (void)in_sizes; (void)n_in; (void)out_size; (void)ws_size;
    const float* x     = (const float*)d_in[0];
    const void*  mask  = d_in[1];
    const float* ln_g  = (const float*)d_in[2];
    const float* ln_b  = (const float*)d_in[3];
    const float* Wl    = (const float*)d_in[4];
    const float* bl    = (const float*)d_in[5];
    const float* Wo    = (const float*)d_in[6];
    const float* bo    = (const float*)d_in[7];
    const float* lno_g = (const float*)d_in[8];
    const float* lno_b = (const float*)d_in[9];

    char* ws = (char*)d_ws;
    float*          lm    = (float*)ws;                              // 1 MB
    unsigned short* woTp  = (unsigned short*)(ws + (size_t)NB * NSEQ * HID * 4);  // 128 KB
    int*            maskr = (int*)(ws + (size_t)NB * NSEQ * HID * 4 + HID * HID * 2);
    float*          cst   = (float*)(ws + (size_t)NB * NSEQ * HID * 4 + HID * HID * 2
                                        + NB * NSEQ * 4);

    prep_kernel<<<NB * NSEQ, 256, 0, stream>>>(x, mask, ln_g, ln_b, Wl, bl, Wo,
                                               lno_b, bo, lm, woTp, maskr, cst);
    outer_kernel<<<NB * BATCH_BLOCKS, 512, 0, stream>>>(
        lm, woTp, lno_g, lno_b, bo, maskr, cst, (float*)d_out);
}

// Round 23
// 143.076 us; speedup vs baseline: 1.2765x; 1.0086x over previous
//
#include <hip/hip_runtime.h>
#include <stdint.h>

#define DIM 256
#define HID 256
#define NSEQ 512
#define NB 2
#define EPS 1e-5f
#define PREP_ROWS 4

typedef __attribute__((ext_vector_type(4))) float f32x4;
typedef __attribute__((ext_vector_type(4))) short bf16x4;
typedef __attribute__((ext_vector_type(8))) short bf16x8;

// Blocks per batch: 512 diagonal (i, jt=i>>6) + 28 pairs * 64 rows = 2304
#define DIAG_BLOCKS 512
#define BATCH_BLOCKS 2304

__device__ __forceinline__ unsigned short f2bf(float f) {
    unsigned int u = __float_as_uint(f);
    u += 0x7fffu + ((u >> 16) & 1u);
    return (unsigned short)(u >> 16);
}

__device__ __forceinline__ float bfval(float f) {
    return __uint_as_float((unsigned)f2bf(f) << 16);
}

// gelu via Abramowitz-Stegun 7.1.26 erf (|abs err| <= 1.5e-7), branchless,
// HW rcp + exp2. R8-R22-proven at the bf16 absmax floor (0.015625).
__device__ __forceinline__ float gelu_fast(float x) {
    const float z  = x * 0.7071067811865476f;
    const float az = fabsf(z);
    const float t  = __builtin_amdgcn_rcpf(fmaf(0.3275911f, az, 1.0f));
    float p = fmaf(1.061405429f, t, -1.453152027f);
    p = fmaf(p, t,  1.421413741f);
    p = fmaf(p, t, -0.284496736f);
    p = fmaf(p, t,  0.254829592f);
    p = p * t;
    const float e = __builtin_amdgcn_exp2f(az * az * -1.4426950408889634f);
    float erfv = fmaf(-p, e, 1.0f);
    erfv = copysignf(erfv, z);
    return 0.5f * x * (1.0f + erfv);
}

// Paired-k position: element k -> 32*(k>>5) + 8*((k>>2)&3) + 4*((k>>4)&1) + (k&3).
__device__ __forceinline__ int pairpos(int k) {
    return ((k >> 5) << 5) + (((k >> 2) & 3) << 3) + (((k >> 4) & 1) << 2) + (k & 3);
}

// Fused prep, 4 rows/block (256 blocks): each thread loads Wl[k][t] ONCE and
// applies it to 4 rows -> Wl L2 traffic 256MB -> 64MB. Per-(row,t) fmaf chain
// is in the same k-ascending order as before -> lm bitwise identical.
// Also: resolved mask -> maskr; blocks with rows < HID emit woTp; block 0
// computes cst[h] = bo[h] + sum_k bf16(lno_b[k]) * bf16(Wo[k][h]).
__global__ __launch_bounds__(256) void prep_kernel(
    const float* __restrict__ x, const void* __restrict__ mask,
    const float* __restrict__ ln_g, const float* __restrict__ ln_b,
    const float* __restrict__ Wl, const float* __restrict__ bl,
    const float* __restrict__ Wo, const float* __restrict__ lno_b,
    const float* __restrict__ bo,
    float* __restrict__ lm, unsigned short* __restrict__ woTp,
    int* __restrict__ maskr, float* __restrict__ cst)
{
    const int row0 = blockIdx.x * PREP_ROWS;     // 256 blocks x 4 rows
    const int t = threadIdx.x;
    const int lane = t & 63, w = t >> 6;
    __shared__ float xs[PREP_ROWS][DIM];
    __shared__ float redS[PREP_ROWS][4], redQ[PREP_ROWS][4];
    __shared__ int bad_s[4];

    // mask layout probe: first 1024 bytes (safe under both layouts).
    {
        const int v = ((const int*)mask)[t];
        unsigned long long bm = __ballot((v & ~1) != 0);
        if (lane == 0) bad_s[w] = (bm != 0ull) ? 1 : 0;
    }

    // Per-row LayerNorm stats (wave-local partials, then one barrier).
    float v[PREP_ROWS];
    #pragma unroll
    for (int r = 0; r < PREP_ROWS; ++r) {
        v[r] = x[(size_t)(row0 + r) * DIM + t];
        float s = v[r], ss = v[r] * v[r];
        #pragma unroll
        for (int o = 32; o; o >>= 1) { s += __shfl_xor(s, o); ss += __shfl_xor(ss, o); }
        if (lane == 0) { redS[r][w] = s; redQ[r][w] = ss; }
    }
    __syncthreads();
    #pragma unroll
    for (int r = 0; r < PREP_ROWS; ++r) {
        const float s  = redS[r][0] + redS[r][1] + redS[r][2] + redS[r][3];
        const float ss = redQ[r][0] + redQ[r][1] + redQ[r][2] + redQ[r][3];
        const float mu  = s * (1.0f / DIM);
        const float var = ss * (1.0f / DIM) - mu * mu;
        const float rs  = rsqrtf(var + EPS);
        xs[r][t] = (v[r] - mu) * rs * ln_g[t] + ln_b[t];
    }
    __syncthreads();

    // Shared-Wl dot: load Wl[k][t] once, apply to all 4 rows.
    float acc[PREP_ROWS];
    #pragma unroll
    for (int r = 0; r < PREP_ROWS; ++r) acc[r] = bl[t];
    #pragma unroll 4
    for (int k = 0; k < DIM; k += 4) {
        const float w0 = Wl[(k + 0) * HID + t];
        const float w1 = Wl[(k + 1) * HID + t];
        const float w2 = Wl[(k + 2) * HID + t];
        const float w3 = Wl[(k + 3) * HID + t];
        #pragma unroll
        for (int r = 0; r < PREP_ROWS; ++r) {
            const float4 xv = *(const float4*)&xs[r][k];
            acc[r] = fmaf(xv.x, w0, acc[r]);
            acc[r] = fmaf(xv.y, w1, acc[r]);
            acc[r] = fmaf(xv.z, w2, acc[r]);
            acc[r] = fmaf(xv.w, w3, acc[r]);
        }
    }

    const int packed = bad_s[0] | bad_s[1] | bad_s[2] | bad_s[3];
    #pragma unroll
    for (int r = 0; r < PREP_ROWS; ++r) {
        const int row = row0 + r;
        const int mv = packed ? (int)((const unsigned char*)mask)[row]
                              : ((const int*)mask)[row];
        lm[(size_t)row * HID + t] = mv ? acc[r] : 0.0f;
        if (t == 0) maskr[row] = mv;
        if (row < HID) {                  // transpose duty
            woTp[row * HID + pairpos(t)] = f2bf(Wo[t * HID + row]);
        }
    }
    if (blockIdx.x == 0) {                // dead-row constant (bf16-rounded inputs)
        float c = bo[t];
        for (int k = 0; k < HID; ++k)
            c = fmaf(bfval(lno_b[k]), bfval(Wo[k * HID + t]), c);
        cst[t] = c;
    }
}

// Main fused kernel: 512 threads / 8 waves (R22 structure, best = 144.3 us).
// Symmetry (R7-verified): upper triangle only; off-diagonal mirror-write.
// Dead-j rows of LIVE blocks store their (constant) output row DURING
// Phase A (~25% of bytes issue in the formerly store-silent phase);
// Phase B skips those rows. Live-row math/stores bitwise identical to R17.
__global__ __launch_bounds__(512) void outer_kernel(
    const float* __restrict__ lm, const unsigned short* __restrict__ woTp,
    const float* __restrict__ lno_g, const float* __restrict__ lno_b,
    const float* __restrict__ bo, const int* __restrict__ maskr,
    const float* __restrict__ cst, float* __restrict__ out)
{
    // ---- block decode: (b, i, jt, mirror) ----
    int blk = (int)blockIdx.x;
    int b = 0;
    if (blk >= BATCH_BLOCKS) { b = 1; blk -= BATCH_BLOCKS; }
    int i, jt, mirror;
    if (blk < DIAG_BLOCKS) {
        i = blk; jt = i >> 6; mirror = 0;
    } else {
        const int r2 = blk - DIAG_BLOCKS;      // 0..1791
        const int p  = r2 >> 6;                // 0..27 pair index (bi,bj), bj>bi
        const int il = r2 & 63;
        int bi = 0, start = 0;
        #pragma unroll
        for (int bb = 0; bb < 7; ++bb) {
            const int s = bb * 7 - (bb * (bb - 1)) / 2;   // 0,7,13,18,22,25,27
            if (p >= s) { bi = bb; start = s; }
        }
        const int bj = bi + 1 + (p - start);
        i = bi * 64 + il;
        jt = bj;
        mirror = 1;
    }
    const int j0  = jt * 64;
    const int t    = threadIdx.x;
    const int lane = t & 63;
    const int w    = t >> 6;              // 0..7
    const size_t base = (size_t)(b * NSEQ + i) * NSEQ * HID;

    const f32x4 cvec = *(const f32x4*)&cst[lane * 4];

    // ---- dead-i fast path: all 64 rows (and mirrors) are the constant row
    if (maskr[b * NSEQ + i] == 0) {
        #pragma unroll
        for (int r = 0; r < 8; ++r) {
            const int j = j0 + w * 8 + r;
            *(f32x4*)&out[base + (size_t)j * HID + lane * 4] = cvec;
            if (mirror)
                *(f32x4*)&out[((size_t)(b * NSEQ + j) * NSEQ + i) * HID + lane * 4] = cvec;
        }
        return;
    }

    __shared__ __align__(16) unsigned char ybuf[64 * 512];  // 64 rows x 256 bf16 (paired-k)

    const float4 li4 = *(const float4*)&lm[(size_t)(b * NSEQ + i) * HID + lane * 4];
    const float4 g4  = *(const float4*)&lno_g[lane * 4];
    const float4 bb4 = *(const float4*)&lno_b[lane * 4];

    // Per-block live-row bitmask: one coalesced load + ballot, no per-row loads.
    const int mvl = maskr[b * NSEQ + j0 + lane];
    const unsigned long long livemask = __ballot(mvl != 0);

    // Paired-k write slot for this lane's k = 4*lane .. 4*lane+3 (8 bytes):
    const int wrb = ((lane >> 3) << 6) + ((lane & 3) << 4) + (((lane >> 2) & 1) << 3);

    // Dead-row Y fragment: y = lno_b exactly (bitwise = full computation)
    const uint2 ucst = make_uint2(
        ((unsigned)f2bf(bb4.y) << 16) | (unsigned)f2bf(bb4.x),
        ((unsigned)f2bf(bb4.w) << 16) | (unsigned)f2bf(bb4.z));

    // ---------------- Phase A: wave w handles local rows [8w, 8w+8).
    // Dead rows: LDS gets the lno_b fragment AND the output row (constant)
    // stores NOW — real store traffic inside the formerly store-silent phase.
    #pragma unroll 4
    for (int r = 0; r < 8; ++r) {
        const int rl = w * 8 + r;
        const int j  = j0 + rl;
        const int off = rl * 512 + (wrb ^ ((rl & 7) << 4));
        if (!((livemask >> rl) & 1ull)) {
            *(uint2*)&ybuf[off] = ucst;
            *(f32x4*)&out[base + (size_t)j * HID + lane * 4] = cvec;
            if (mirror)
                *(f32x4*)&out[((size_t)(b * NSEQ + j) * NSEQ + i) * HID + lane * 4] = cvec;
            continue;
        }
        float4 lj4 = *(const float4*)&lm[(size_t)(b * NSEQ + j) * HID + lane * 4];
        float4 p;
        p.x = gelu_fast(li4.x * lj4.x);
        p.y = gelu_fast(li4.y * lj4.y);
        p.z = gelu_fast(li4.z * lj4.z);
        p.w = gelu_fast(li4.w * lj4.w);
        float s  = p.x + p.y + p.z + p.w;
        float ss = p.x * p.x + p.y * p.y + p.z * p.z + p.w * p.w;
        #pragma unroll
        for (int o = 32; o; o >>= 1) { s += __shfl_xor(s, o); ss += __shfl_xor(ss, o); }
        const float mu  = s * (1.0f / HID);
        const float var = ss * (1.0f / HID) - mu * mu;
        const float rs  = rsqrtf(var + EPS);
        const float y0 = (p.x - mu) * rs * g4.x + bb4.x;
        const float y1 = (p.y - mu) * rs * g4.y + bb4.y;
        const float y2 = (p.z - mu) * rs * g4.z + bb4.z;
        const float y3 = (p.w - mu) * rs * g4.w + bb4.w;
        const unsigned int u0 = ((unsigned)f2bf(y1) << 16) | (unsigned)f2bf(y0);
        const unsigned int u1 = ((unsigned)f2bf(y3) << 16) | (unsigned)f2bf(y2);
        *(uint2*)&ybuf[off] = make_uint2(u0, u1);
    }
    __syncthreads();

    // ---------------- Phase B: wave w owns cols [32w, 32w+32), all 64 j rows
    const int n0  = w * 32;
    const int l15 = lane & 15;
    const int q   = lane >> 4;           // 0..3

    f32x4 acc[4][2];
    #pragma unroll
    for (int mi = 0; mi < 4; ++mi)
        #pragma unroll
        for (int nh = 0; nh < 2; ++nh)
            acc[mi][nh] = (f32x4){0.f, 0.f, 0.f, 0.f};

#if !__has_builtin(__builtin_amdgcn_mfma_f32_16x16x16bf16_1k)
    #pragma unroll
    for (int mi = 0; mi < 4; ++mi)
        #pragma unroll
        for (int nh = 0; nh < 2; ++nh)
            asm volatile("" : "+v"(acc[mi][nh]));
    asm volatile("s_nop 1");
#endif

    #pragma unroll
    for (int kk2 = 0; kk2 < 8; ++kk2) {        // K = 256, 2 k-steps per iter
        const int pb = kk2 * 64 + q * 16;      // paired-k byte offset within row
        bf16x8 a8[4], b8[2];
        #pragma unroll
        for (int mi = 0; mi < 4; ++mi) {
            const int rowm = mi * 16 + l15;
            a8[mi] = *(const bf16x8*)&ybuf[rowm * 512 + (pb ^ ((rowm & 7) << 4))];
        }
        #pragma unroll
        for (int nh = 0; nh < 2; ++nh) {
            const int col = n0 + nh * 16 + l15;
            b8[nh] = *(const bf16x8*)&woTp[col * HID + kk2 * 32 + q * 8];
        }
        #pragma unroll
        for (int mi = 0; mi < 4; ++mi) {
            const bf16x4 alo = __builtin_shufflevector(a8[mi], a8[mi], 0, 1, 2, 3);
            const bf16x4 ahi = __builtin_shufflevector(a8[mi], a8[mi], 4, 5, 6, 7);
            #pragma unroll
            for (int nh = 0; nh < 2; ++nh) {
                const bf16x4 blo = __builtin_shufflevector(b8[nh], b8[nh], 0, 1, 2, 3);
                const bf16x4 bhi = __builtin_shufflevector(b8[nh], b8[nh], 4, 5, 6, 7);
#if __has_builtin(__builtin_amdgcn_mfma_f32_16x16x16bf16_1k)
                acc[mi][nh] = __builtin_amdgcn_mfma_f32_16x16x16bf16_1k(
                    blo, alo, acc[mi][nh], 0, 0, 0);
                acc[mi][nh] = __builtin_amdgcn_mfma_f32_16x16x16bf16_1k(
                    bhi, ahi, acc[mi][nh], 0, 0, 0);
#else
                asm volatile("v_mfma_f32_16x16x16_bf16 %0, %1, %2, %0"
                             : "+v"(acc[mi][nh]) : "v"(blo), "v"(alo));
                asm volatile("v_mfma_f32_16x16x16_bf16 %0, %1, %2, %0"
                             : "+v"(acc[mi][nh]) : "v"(bhi), "v"(ahi));
#endif
            }
        }
    }

#if !__has_builtin(__builtin_amdgcn_mfma_f32_16x16x16bf16_1k)
    asm volatile("s_nop 7");
    asm volatile("s_nop 7");
    #pragma unroll
    for (int mi = 0; mi < 4; ++mi)
        #pragma unroll
        for (int nh = 0; nh < 2; ++nh)
            asm volatile("" : "+v"(acc[mi][nh]));
#endif

    // Stores: lane l, reg r -> j = j0 + mi*16 + (l&15), h = n0 + nh*16 + 4q + r.
    // Dead rows were already written in Phase A -> per-lane predicate skips them.
    #pragma unroll
    for (int mi = 0; mi < 4; ++mi) {
        const int rowm = mi * 16 + l15;
        if (!((livemask >> rowm) & 1ull)) continue;   // written during Phase A
        const int j = j0 + rowm;
        const size_t prow = base + (size_t)j * HID;
        const size_t mrow = ((size_t)(b * NSEQ + j) * NSEQ + i) * HID;
        #pragma unroll
        for (int nh = 0; nh < 2; ++nh) {
            const int h0 = n0 + nh * 16 + q * 4;
            const float4 bo4 = *(const float4*)&bo[h0];
            f32x4 o;
            o[0] = acc[mi][nh][0] + bo4.x;
            o[1] = acc[mi][nh][1] + bo4.y;
            o[2] = acc[mi][nh][2] + bo4.z;
            o[3] = acc[mi][nh][3] + bo4.w;
            *(f32x4*)&out[prow + h0] = o;
            if (mirror)
                *(f32x4*)&out[mrow + h0] = o;
        }
    }
}

extern "C" void kernel_launch(void* const* d_in, const int* in_sizes, int n_in,
                              void* d_out, int out_size, void* d_ws, size_t ws_size,
                              hipStream_t stream) {
    (void)in_sizes; (void)n_in; (void)out_size; (void)ws_size;
    const float* x     = (const float*)d_in[0];
    const void*  mask  = d_in[1];
    const float* ln_g  = (const float*)d_in[2];
    const float* ln_b  = (const float*)d_in[3];
    const float* Wl    = (const float*)d_in[4];
    const float* bl    = (const float*)d_in[5];
    const float* Wo    = (const float*)d_in[6];
    const float* bo    = (const float*)d_in[7];
    const float* lno_g = (const float*)d_in[8];
    const float* lno_b = (const float*)d_in[9];

    char* ws = (char*)d_ws;
    float*          lm    = (float*)ws;                              // 1 MB
    unsigned short* woTp  = (unsigned short*)(ws + (size_t)NB * NSEQ * HID * 4);  // 128 KB
    int*            maskr = (int*)(ws + (size_t)NB * NSEQ * HID * 4 + HID * HID * 2);
    float*          cst   = (float*)(ws + (size_t)NB * NSEQ * HID * 4 + HID * HID * 2
                                        + NB * NSEQ * 4);

    prep_kernel<<<NB * NSEQ / PREP_ROWS, 256, 0, stream>>>(
        x, mask, ln_g, ln_b, Wl, bl, Wo, lno_b, bo, lm, woTp, maskr, cst);
    outer_kernel<<<NB * BATCH_BLOCKS, 512, 0, stream>>>(
        lm, woTp, lno_g, lno_b, bo, maskr, cst, (float*)d_out);
}